// Round 5
// baseline (48.458 us; speedup 1.0000x reference)
//
#include <hip/hip_runtime.h>
#include <hip/hip_bf16.h>

typedef __attribute__((ext_vector_type(8))) short short8;
typedef __attribute__((ext_vector_type(4))) float floatx4;

#define B_ROWS 8192
#define DIM 128
#define NPAIR 4095
// rows scaled by sqrt(log2(e)) so S_mfma = S * log2(e) and exp(S) = exp2(S_mfma)
#define RSCALE 1.2011224087864498f

// ---------------- zero Z (fallback path only) ----------------
__global__ void kzero(float* __restrict__ Z) {
    int i = blockIdx.x * 256 + threadIdx.x;
    if (i < B_ROWS) Z[i] = 0.f;
}

// ------------- fused prep: normalize rows -> bf16 (scaled), pair dots, zero out -------------
__global__ void kprep(const float* __restrict__ X, __hip_bfloat16* __restrict__ XN,
                      float* __restrict__ pairT, float* __restrict__ out) {
    __shared__ float2 lds[4][64];
    const int wid = threadIdx.x >> 6;
    const int lane = threadIdx.x & 63;
    const int row = blockIdx.x * 4 + wid;

    const float2 v = *reinterpret_cast<const float2*>(X + row * DIM + lane * 2);
    float ss = v.x * v.x + v.y * v.y;
    #pragma unroll
    for (int m = 1; m < 64; m <<= 1) ss += __shfl_xor(ss, m, 64);
    const float rn = ss > 0.f ? rsqrtf(ss) : 0.f;
    const float2 nv = make_float2(v.x * rn, v.y * rn);

    *reinterpret_cast<__hip_bfloat162*>(XN + row * DIM + lane * 2) =
        __float22bfloat162_rn(make_float2(nv.x * RSCALE, nv.y * RSCALE));
    lds[wid][lane] = nv;  // unscaled for exact pair dot
    __syncthreads();

    if ((wid & 1) == 0) {
        const int p = blockIdx.x * 2 + (wid >> 1);
        if (p < NPAIR) {
            const float2 a = lds[wid][lane];
            const float2 b = lds[wid + 1][lane];
            float d = a.x * b.x + a.y * b.y;
            #pragma unroll
            for (int m = 1; m < 64; m <<= 1) d += __shfl_xor(d, m, 64);
            if (lane == 0) pairT[p] = d;
        }
    }
    if (blockIdx.x == 0 && threadIdx.x == 0) out[0] = 0.f;
}

// ------------- main: row-panel GEMM, low register pressure, pipelined B -------------
// grid (8, 64): y = row panel rb (128 rows), x = col group g (8 tiles of 128 cols).
// 4 waves/block in a 2x2 (wr, wc) split: wave owns 64 rows x 64 cols per tile,
// processed as two 32-col halves with ping-pong B buffers.
// VGPR budget: a 64 + bA 32 + bB 32 + acc 32 + rp 16 + temps ~ 210 (no spill at 256).
template <bool USEP>
__global__ void __launch_bounds__(256, 2) kgemm(const __hip_bfloat16* __restrict__ XN,
                                                float* __restrict__ ZP) {
    const int wid = threadIdx.x >> 6;
    const int lane = threadIdx.x & 63;
    const int lr = lane & 15;
    const int lk = lane >> 4;
    const int wr = wid >> 1;
    const int wc = wid & 1;
    const int rb = blockIdx.y;
    const int g = blockIdx.x;

    // ---- A: 64 rows, loaded once: a[kk][m], rows rb*128 + wr*64 + m*16 + lr ----
    short8 a[4][4];
    const __hip_bfloat16* Abase = XN + (rb * 128 + wr * 64 + lr) * DIM + lk * 8;
    #pragma unroll
    for (int m = 0; m < 4; ++m)
        #pragma unroll
        for (int kk = 0; kk < 4; ++kk)
            a[kk][m] = *reinterpret_cast<const short8*>(Abase + m * 16 * DIM + kk * 32);

    float rp[4][4];
    #pragma unroll
    for (int m = 0; m < 4; ++m)
        #pragma unroll
        for (int r = 0; r < 4; ++r) rp[m][r] = 0.f;

    // wave's col slice base: col = wc*64 (+ h*32 + n*16 + lr)
    const __hip_bfloat16* Bcol = XN + (wc * 64 + lr) * DIM + lk * 8;

    const floatx4 zero4 = {0.f, 0.f, 0.f, 0.f};
    short8 bA[4][2], bB[4][2];

    // prologue: (tile 0, half 0) -> bA
    {
        const __hip_bfloat16* Bj = Bcol + (g * 8) * 128 * DIM;
        #pragma unroll
        for (int n = 0; n < 2; ++n)
            #pragma unroll
            for (int kk = 0; kk < 4; ++kk)
                bA[kk][n] = *reinterpret_cast<const short8*>(Bj + n * 16 * DIM + kk * 32);
    }

    for (int j = 0; j < 8; ++j) {
        const int cbj = g * 8 + j;
        const __hip_bfloat16* Bj = Bcol + cbj * 128 * DIM;
        const bool dtile = (cbj == rb) && (wr == wc);

        // issue half-1 loads (overlap half-0 compute)
        #pragma unroll
        for (int n = 0; n < 2; ++n)
            #pragma unroll
            for (int kk = 0; kk < 4; ++kk)
                bB[kk][n] = *reinterpret_cast<const short8*>(Bj + (32 + n * 16) * DIM + kk * 32);

        // ---- half 0 ----
        floatx4 acc[4][2];
        #pragma unroll
        for (int m = 0; m < 4; ++m)
            #pragma unroll
            for (int n = 0; n < 2; ++n)
                acc[m][n] = __builtin_amdgcn_mfma_f32_16x16x32_bf16(a[0][m], bA[0][n], zero4, 0, 0, 0);
        #pragma unroll
        for (int kk = 1; kk < 4; ++kk)
            #pragma unroll
            for (int m = 0; m < 4; ++m)
                #pragma unroll
                for (int n = 0; n < 2; ++n)
                    acc[m][n] = __builtin_amdgcn_mfma_f32_16x16x32_bf16(a[kk][m], bA[kk][n], acc[m][n], 0, 0, 0);

        if (dtile) {
            #pragma unroll
            for (int m = 0; m < 4; ++m)
                #pragma unroll
                for (int n = 0; n < 2; ++n)
                    #pragma unroll
                    for (int r = 0; r < 4; ++r) {
                        float e = __builtin_amdgcn_exp2f(acc[m][n][r]);
                        if (m * 16 + lk * 4 + r == n * 16 + lr) e = 0.f;
                        rp[m][r] += e;
                    }
        } else {
            #pragma unroll
            for (int m = 0; m < 4; ++m)
                #pragma unroll
                for (int n = 0; n < 2; ++n)
                    #pragma unroll
                    for (int r = 0; r < 4; ++r)
                        rp[m][r] += __builtin_amdgcn_exp2f(acc[m][n][r]);
        }

        // issue half-0 loads for NEXT tile (overlap half-1 compute)
        if (j < 7) {
            const __hip_bfloat16* Bn = Bcol + (cbj + 1) * 128 * DIM;
            #pragma unroll
            for (int n = 0; n < 2; ++n)
                #pragma unroll
                for (int kk = 0; kk < 4; ++kk)
                    bA[kk][n] = *reinterpret_cast<const short8*>(Bn + n * 16 * DIM + kk * 32);
        }

        // ---- half 1 ----
        #pragma unroll
        for (int m = 0; m < 4; ++m)
            #pragma unroll
            for (int n = 0; n < 2; ++n)
                acc[m][n] = __builtin_amdgcn_mfma_f32_16x16x32_bf16(a[0][m], bB[0][n], zero4, 0, 0, 0);
        #pragma unroll
        for (int kk = 1; kk < 4; ++kk)
            #pragma unroll
            for (int m = 0; m < 4; ++m)
                #pragma unroll
                for (int n = 0; n < 2; ++n)
                    acc[m][n] = __builtin_amdgcn_mfma_f32_16x16x32_bf16(a[kk][m], bB[kk][n], acc[m][n], 0, 0, 0);

        if (dtile) {
            #pragma unroll
            for (int m = 0; m < 4; ++m)
                #pragma unroll
                for (int n = 0; n < 2; ++n)
                    #pragma unroll
                    for (int r = 0; r < 4; ++r) {
                        float e = __builtin_amdgcn_exp2f(acc[m][n][r]);
                        if (m * 16 + lk * 4 + r == 32 + n * 16 + lr) e = 0.f;
                        rp[m][r] += e;
                    }
        } else {
            #pragma unroll
            for (int m = 0; m < 4; ++m)
                #pragma unroll
                for (int n = 0; n < 2; ++n)
                    #pragma unroll
                    for (int r = 0; r < 4; ++r)
                        rp[m][r] += __builtin_amdgcn_exp2f(acc[m][n][r]);
        }
    }

    // ---- row sums: reduce over lr, store slot (g*2 + wc) ----
    #pragma unroll
    for (int m = 0; m < 4; ++m)
        #pragma unroll
        for (int r = 0; r < 4; ++r) {
            float v = rp[m][r];
            v += __shfl_xor(v, 1, 64);
            v += __shfl_xor(v, 2, 64);
            v += __shfl_xor(v, 4, 64);
            v += __shfl_xor(v, 8, 64);
            if (lr == 0) {
                const int row = rb * 128 + wr * 64 + m * 16 + lk * 4 + r;
                if (USEP)
                    ZP[(g * 2 + wc) * B_ROWS + row] = v;
                else
                    atomicAdd(&ZP[row], v);
            }
        }
}

// ------------- final (P path): Z[r] = sum_{16 slots} P[t][r]; loss reduce -------------
__global__ void kfinalP(const float* __restrict__ P, const float* __restrict__ pairT,
                        float* __restrict__ out) {
    const int r = blockIdx.x * 256 + threadIdx.x;
    float s = 0.f;
    if (r < B_ROWS - 2) {
        float z = 0.f;
        #pragma unroll
        for (int tt = 0; tt < 16; ++tt) z += P[tt * B_ROWS + r];
        s = logf(z);
    }
    if (r < NPAIR) s -= 2.f * pairT[r];
    #pragma unroll
    for (int m = 1; m < 64; m <<= 1) s += __shfl_xor(s, m, 64);
    __shared__ float red[4];
    const int wid = threadIdx.x >> 6;
    const int lane = threadIdx.x & 63;
    if (lane == 0) red[wid] = s;
    __syncthreads();
    if (threadIdx.x == 0) {
        float tsum = red[0] + red[1] + red[2] + red[3];
        atomicAdd(out, tsum / (float)B_ROWS);
    }
}

// ------------- final (Z fallback path) -------------
__global__ void kfinalZ(const float* __restrict__ Z, const float* __restrict__ pairT,
                        float* __restrict__ out) {
    float s = 0.f;
    for (int r = threadIdx.x; r < B_ROWS - 2; r += 1024) s += logf(Z[r]);
    for (int p = threadIdx.x; p < NPAIR; p += 1024) s -= 2.f * pairT[p];
    #pragma unroll
    for (int m = 1; m < 64; m <<= 1) s += __shfl_xor(s, m, 64);
    __shared__ float red[16];
    const int wid = threadIdx.x >> 6;
    const int lane = threadIdx.x & 63;
    if (lane == 0) red[wid] = s;
    __syncthreads();
    if (threadIdx.x == 0) {
        float t = 0.f;
        #pragma unroll
        for (int i = 0; i < 16; ++i) t += red[i];
        out[0] = t / (float)B_ROWS;
    }
}

extern "C" void kernel_launch(void* const* d_in, const int* in_sizes, int n_in,
                              void* d_out, int out_size, void* d_ws, size_t ws_size,
                              hipStream_t stream) {
    (void)in_sizes; (void)n_in; (void)out_size;
    const float* X = (const float*)d_in[0];
    float* out = (float*)d_out;
    char* ws = (char*)d_ws;

    float* Z = (float*)ws;                                   // 32 KB
    float* pairT = (float*)(ws + 32768);                     // 16 KB
    __hip_bfloat16* XN = (__hip_bfloat16*)(ws + 49152);      // 2 MB
    float* P = (float*)(ws + 49152 + 2097152);               // 512 KB (16 x 8192 f32)
    const size_t need = 49152 + 2097152 + (size_t)16 * B_ROWS * 4;
    const bool useP = ws_size >= need;

    kprep<<<2048, 256, 0, stream>>>(X, XN, pairT, out);
    if (useP) {
        kgemm<true><<<dim3(8, 64), 256, 0, stream>>>(XN, P);
        kfinalP<<<32, 256, 0, stream>>>(P, pairT, out);
    } else {
        kzero<<<32, 256, 0, stream>>>(Z);
        kgemm<false><<<dim3(8, 64), 256, 0, stream>>>(XN, Z);
        kfinalZ<<<1, 1024, 0, stream>>>(Z, pairT, out);
    }
}

// Round 6
// 34.295 us; speedup vs baseline: 1.4130x; 1.4130x over previous
//
#include <hip/hip_runtime.h>
#include <hip/hip_bf16.h>

typedef __attribute__((ext_vector_type(8))) short short8;
typedef __attribute__((ext_vector_type(4))) float floatx4;

#define B_ROWS 8192
#define DIM 128
#define NPAIR 4095
// rows scaled by sqrt(log2(e)) so S_mfma = S * log2(e) and exp(S) = exp2(S_mfma)
#define RSCALE 1.2011224087864498f

#define GLOAD_LDS16(gp, lp)                                                     \
    __builtin_amdgcn_global_load_lds(                                           \
        (const __attribute__((address_space(1))) void*)(gp),                    \
        (__attribute__((address_space(3))) void*)(lp), 16, 0, 0)

// ---------------- zero Z (fallback path only) ----------------
__global__ void kzero(float* __restrict__ Z) {
    int i = blockIdx.x * 256 + threadIdx.x;
    if (i < B_ROWS) Z[i] = 0.f;
}

// ------------- fused prep: normalize rows -> bf16 (scaled), pair dots, zero out -------------
__global__ void kprep(const float* __restrict__ X, __hip_bfloat16* __restrict__ XN,
                      float* __restrict__ pairT, float* __restrict__ out) {
    __shared__ float2 lds[4][64];
    const int wid = threadIdx.x >> 6;
    const int lane = threadIdx.x & 63;
    const int row = blockIdx.x * 4 + wid;

    const float2 v = *reinterpret_cast<const float2*>(X + row * DIM + lane * 2);
    float ss = v.x * v.x + v.y * v.y;
    #pragma unroll
    for (int m = 1; m < 64; m <<= 1) ss += __shfl_xor(ss, m, 64);
    const float rn = ss > 0.f ? rsqrtf(ss) : 0.f;
    const float2 nv = make_float2(v.x * rn, v.y * rn);

    *reinterpret_cast<__hip_bfloat162*>(XN + row * DIM + lane * 2) =
        __float22bfloat162_rn(make_float2(nv.x * RSCALE, nv.y * RSCALE));
    lds[wid][lane] = nv;  // unscaled for exact pair dot
    __syncthreads();

    if ((wid & 1) == 0) {
        const int p = blockIdx.x * 2 + (wid >> 1);
        if (p < NPAIR) {
            const float2 a = lds[wid][lane];
            const float2 b = lds[wid + 1][lane];
            float d = a.x * b.x + a.y * b.y;
            #pragma unroll
            for (int m = 1; m < 64; m <<= 1) d += __shfl_xor(d, m, 64);
            if (lane == 0) pairT[p] = d;
        }
    }
    if (blockIdx.x == 0 && threadIdx.x == 0) out[0] = 0.f;
}

// ---- stage one 128x128 bf16 tile to LDS (linear dest, pre-swizzled source) ----
// LDS[row][colL] = global[row][colL ^ ((row&7)<<3)]  (8-elem-group XOR swizzle)
__device__ __forceinline__ void stage_tile(const __hip_bfloat16* __restrict__ gsrc,
                                           __hip_bfloat16* lbuf, int tid) {
    const int wid = tid >> 6;
    const int lane = tid & 63;
    #pragma unroll
    for (int it = 0; it < 8; ++it) {
        const int woff = it * 2048 + wid * 512;  // wave-uniform elem offset
        const int e = woff + lane * 8;
        const int src = (e & ~127) | ((e & 127) ^ (((e >> 7) & 7) << 3));
        GLOAD_LDS16(gsrc + src, lbuf + woff);
    }
}

// ------------- main: row-panel GEMM, A in regs, B double-buffered LDS (T3 2-phase) -------------
// grid (8, 64): y = row panel rb (128 rows), x = col group g (8 tiles of 128 cols).
// 4 waves 2x2: wave owns 64 rows x 64 cols per tile, processed as two 32-col halves.
template <bool USEP>
__global__ void __launch_bounds__(256, 2) kgemm(const __hip_bfloat16* __restrict__ XN,
                                                float* __restrict__ ZP) {
    __shared__ __hip_bfloat16 Bs[2][128 * DIM];

    const int tid = threadIdx.x;
    const int wid = tid >> 6;
    const int lane = tid & 63;
    const int lr = lane & 15;
    const int lk = lane >> 4;
    const int wr = wid >> 1;
    const int wc = wid & 1;
    const int rb = blockIdx.y;
    const int g = blockIdx.x;

    // ---- A: 64 rows in registers: a[kk][m], rows rb*128 + wr*64 + m*16 + lr ----
    short8 a[4][4];
    const __hip_bfloat16* Abase = XN + (rb * 128 + wr * 64 + lr) * DIM + lk * 8;
    #pragma unroll
    for (int m = 0; m < 4; ++m)
        #pragma unroll
        for (int kk = 0; kk < 4; ++kk)
            a[kk][m] = *reinterpret_cast<const short8*>(Abase + m * 16 * DIM + kk * 32);

    float rp[4][4];
    #pragma unroll
    for (int m = 0; m < 4; ++m)
        #pragma unroll
        for (int r = 0; r < 4; ++r) rp[m][r] = 0.f;

    const floatx4 zero4 = {0.f, 0.f, 0.f, 0.f};

    // prologue: stage tile 0
    stage_tile(XN + (g * 8) * 128 * DIM, Bs[0], tid);
    __syncthreads();

    for (int j = 0; j < 8; ++j) {
        const int cur = j & 1;
        // issue next-tile DMA first: overlaps this tile's ds_read + MFMA + exp
        if (j < 7)
            stage_tile(XN + (g * 8 + j + 1) * 128 * DIM, Bs[cur ^ 1], tid);

        const int cbj = g * 8 + j;
        const bool dtile = (cbj == rb) && (wr == wc);
        const __hip_bfloat16* Bt = Bs[cur];

        #pragma unroll
        for (int h = 0; h < 2; ++h) {
            // B fragments for cols wc*64 + (h*2+n)*16 + lr, swizzled read
            short8 b[4][2];
            #pragma unroll
            for (int n = 0; n < 2; ++n) {
                const int row = wc * 64 + (h * 2 + n) * 16 + lr;
                #pragma unroll
                for (int kk = 0; kk < 4; ++kk) {
                    const int col = (kk * 32 + lk * 8) ^ ((row & 7) << 3);
                    b[kk][n] = *reinterpret_cast<const short8*>(&Bt[row * DIM + col]);
                }
            }
            floatx4 acc[4][2];
            #pragma unroll
            for (int m = 0; m < 4; ++m)
                #pragma unroll
                for (int n = 0; n < 2; ++n)
                    acc[m][n] = __builtin_amdgcn_mfma_f32_16x16x32_bf16(a[0][m], b[0][n], zero4, 0, 0, 0);
            #pragma unroll
            for (int kk = 1; kk < 4; ++kk)
                #pragma unroll
                for (int m = 0; m < 4; ++m)
                    #pragma unroll
                    for (int n = 0; n < 2; ++n)
                        acc[m][n] = __builtin_amdgcn_mfma_f32_16x16x32_bf16(a[kk][m], b[kk][n], acc[m][n], 0, 0, 0);

            if (dtile) {
                #pragma unroll
                for (int m = 0; m < 4; ++m)
                    #pragma unroll
                    for (int n = 0; n < 2; ++n)
                        #pragma unroll
                        for (int r = 0; r < 4; ++r) {
                            float e = __builtin_amdgcn_exp2f(acc[m][n][r]);
                            if (m == (h * 2 + n) && (lk * 4 + r) == lr) e = 0.f;
                            rp[m][r] += e;
                        }
            } else {
                #pragma unroll
                for (int m = 0; m < 4; ++m)
                    #pragma unroll
                    for (int n = 0; n < 2; ++n)
                        #pragma unroll
                        for (int r = 0; r < 4; ++r)
                            rp[m][r] += __builtin_amdgcn_exp2f(acc[m][n][r]);
            }
        }
        // single barrier per tile: drains this wave's DMA (vmcnt) and orders buffers
        __syncthreads();
    }

    // ---- row sums: reduce over lr, store slot (g*2 + wc) ----
    #pragma unroll
    for (int m = 0; m < 4; ++m)
        #pragma unroll
        for (int r = 0; r < 4; ++r) {
            float v = rp[m][r];
            v += __shfl_xor(v, 1, 64);
            v += __shfl_xor(v, 2, 64);
            v += __shfl_xor(v, 4, 64);
            v += __shfl_xor(v, 8, 64);
            if (lr == 0) {
                const int row = rb * 128 + wr * 64 + m * 16 + lk * 4 + r;
                if (USEP)
                    ZP[(g * 2 + wc) * B_ROWS + row] = v;
                else
                    atomicAdd(&ZP[row], v);
            }
        }
}

// ------------- final (P path): Z[r] = sum_{16 slots} P[t][r]; loss reduce -------------
__global__ void kfinalP(const float* __restrict__ P, const float* __restrict__ pairT,
                        float* __restrict__ out) {
    const int r = blockIdx.x * 256 + threadIdx.x;
    float s = 0.f;
    if (r < B_ROWS - 2) {
        float z = 0.f;
        #pragma unroll
        for (int tt = 0; tt < 16; ++tt) z += P[tt * B_ROWS + r];
        s = logf(z);
    }
    if (r < NPAIR) s -= 2.f * pairT[r];
    #pragma unroll
    for (int m = 1; m < 64; m <<= 1) s += __shfl_xor(s, m, 64);
    __shared__ float red[4];
    const int wid = threadIdx.x >> 6;
    const int lane = threadIdx.x & 63;
    if (lane == 0) red[wid] = s;
    __syncthreads();
    if (threadIdx.x == 0) {
        float tsum = red[0] + red[1] + red[2] + red[3];
        atomicAdd(out, tsum / (float)B_ROWS);
    }
}

// ------------- final (Z fallback path) -------------
__global__ void kfinalZ(const float* __restrict__ Z, const float* __restrict__ pairT,
                        float* __restrict__ out) {
    float s = 0.f;
    for (int r = threadIdx.x; r < B_ROWS - 2; r += 1024) s += logf(Z[r]);
    for (int p = threadIdx.x; p < NPAIR; p += 1024) s -= 2.f * pairT[p];
    #pragma unroll
    for (int m = 1; m < 64; m <<= 1) s += __shfl_xor(s, m, 64);
    __shared__ float red[16];
    const int wid = threadIdx.x >> 6;
    const int lane = threadIdx.x & 63;
    if (lane == 0) red[wid] = s;
    __syncthreads();
    if (threadIdx.x == 0) {
        float t = 0.f;
        #pragma unroll
        for (int i = 0; i < 16; ++i) t += red[i];
        out[0] = t / (float)B_ROWS;
    }
}

extern "C" void kernel_launch(void* const* d_in, const int* in_sizes, int n_in,
                              void* d_out, int out_size, void* d_ws, size_t ws_size,
                              hipStream_t stream) {
    (void)in_sizes; (void)n_in; (void)out_size;
    const float* X = (const float*)d_in[0];
    float* out = (float*)d_out;
    char* ws = (char*)d_ws;

    float* Z = (float*)ws;                                   // 32 KB
    float* pairT = (float*)(ws + 32768);                     // 16 KB
    __hip_bfloat16* XN = (__hip_bfloat16*)(ws + 49152);      // 2 MB
    float* P = (float*)(ws + 49152 + 2097152);               // 512 KB (16 x 8192 f32)
    const size_t need = 49152 + 2097152 + (size_t)16 * B_ROWS * 4;
    const bool useP = ws_size >= need;

    kprep<<<2048, 256, 0, stream>>>(X, XN, pairT, out);
    if (useP) {
        kgemm<true><<<dim3(8, 64), 256, 0, stream>>>(XN, P);
        kfinalP<<<32, 256, 0, stream>>>(P, pairT, out);
    } else {
        kzero<<<32, 256, 0, stream>>>(Z);
        kgemm<false><<<dim3(8, 64), 256, 0, stream>>>(XN, Z);
        kfinalZ<<<1, 1024, 0, stream>>>(Z, pairT, out);
    }
}